// Round 6
// baseline (373.623 us; speedup 1.0000x reference)
//
#include <hip/hip_runtime.h>
#include <math.h>

// Net (per image b of 256):  x: (dh=256, wt=256), dh=d*16+h, wt=w*16+t
//  L1: w1 (17,17,9,9) pad4 -> (dh_o=64, wt=256) relu      [MFMA, 81 taps, K=256]
//  L2: w2 (7,7,7,7)  pad3 -> same, relu                   [MFMA, 49 taps, K=64]
//  L3: w3 (5,5,5,5)  pad2 -> relu
//  L4: w4 (3,3,3,3)  pad1 -> relu
//  L5: w5 (8,8)      -> sigmoid -> out (256,16,16)
//
// R6: L1 is B-operand-bandwidth bound (R4/R5 evidence: time tracks B-traffic
// = waves x 8KB/tap). Fix: 2 images/block, wave m=8 tiles (B-frag feeds 64
// MFMA) -> B/img/qtap halves to 16 KB. Grid stays 256 via K-half split with
// fp32 partials (P0 aliases act buffer; reduce_l1 adds + bias + relu).
// XT: 2img x 256row x 64dh bf16 = exactly 64 KB, XOR-swizzled (unit^row&7)
// instead of padded -> conflict-free stage-writes and b128 reads; OOB taps
// masked in registers (no zero row). B register-double-buffered; A inline.

typedef short bf16x8 __attribute__((ext_vector_type(8)));
typedef float f32x4 __attribute__((ext_vector_type(4)));
typedef unsigned int u32x4 __attribute__((ext_vector_type(4)));

__device__ __forceinline__ unsigned short f2bf(float f) {
  unsigned int u = __float_as_uint(f);
  u += 0x7fffu + ((u >> 16) & 1u);  // RNE
  return (unsigned short)(u >> 16);
}

// ---------------- B-matrix precompute (unchanged layouts from R4) ------------
template <int KSZ, int PAD>
__device__ __forceinline__ void build_mid(const float* __restrict__ w,
                                          unsigned short* __restrict__ Bg, int gid) {
  const int lane = gid & 63;
  const int n_tile = (gid >> 6) & 3;
  const int chunk = (gid >> 8) & 1;
  const int tap = gid >> 9;
  const int kw = tap / KSZ, kt = tap - kw * KSZ;
  const int dh_o = n_tile * 16 + (lane & 15);
  const int d_o = dh_o >> 3, h_o = dh_o & 7;
  const int kbase = chunk * 32 + (lane >> 4) * 8;
  unsigned int pk[4];
#pragma unroll
  for (int p = 0; p < 4; ++p) {
    unsigned short half[2];
#pragma unroll
    for (int s = 0; s < 2; ++s) {
      const int k = kbase + p * 2 + s;
      const int d_i = k >> 3, h_i = k & 7;
      const int kd = d_i - d_o + PAD, kh = h_i - h_o + PAD;
      float v = 0.f;
      if (kd >= 0 && kd < KSZ && kh >= 0 && kh < KSZ)
        v = w[((kd * KSZ + kh) * KSZ + kw) * KSZ + kt];
      half[s] = f2bf(v);
    }
    pk[p] = (unsigned int)half[0] | ((unsigned int)half[1] << 16);
  }
  *(int4*)(Bg + (size_t)gid * 8) = make_int4(pk[0], pk[1], pk[2], pk[3]);
}

__global__ __launch_bounds__(256) void build_all(const float* __restrict__ w1,
                                                 const float* __restrict__ w2,
                                                 const float* __restrict__ w3,
                                                 const float* __restrict__ w4,
                                                 unsigned short* __restrict__ Bg1,
                                                 unsigned short* __restrict__ Bg2,
                                                 unsigned short* __restrict__ Bg3,
                                                 unsigned short* __restrict__ Bg4) {
  const int bid = blockIdx.x, tid = threadIdx.x;
  if (bid < 648) {  // L1: 81 taps * 8 chunks * 4 ntiles * 64 lanes
    const int gid = bid * 256 + tid;
    const int lane = gid & 63;
    const int n_tile = (gid >> 6) & 3;
    const int chunk = (gid >> 8) & 7;
    const int kwkt = gid >> 11;
    const int kw = kwkt / 9, kt = kwkt - kw * 9;
    const int dh_o = n_tile * 16 + (lane & 15);
    const int d_o = dh_o >> 3, h_o = dh_o & 7;
    const int kbase = chunk * 32 + (lane >> 4) * 8;
    unsigned int pk[4];
#pragma unroll
    for (int p = 0; p < 4; ++p) {
      unsigned short half[2];
#pragma unroll
      for (int s = 0; s < 2; ++s) {
        const int k = kbase + p * 2 + s;
        const int d_i = k >> 4, h_i = k & 15;
        const int kd = d_i - d_o + 4, kh = h_i - h_o + 4;
        float v = 0.f;
        if (kd >= 0 && kd < 17 && kh >= 0 && kh < 17)
          v = w1[((kd * 17 + kh) * 9 + kw) * 9 + kt];
        half[s] = f2bf(v);
      }
      pk[p] = (unsigned int)half[0] | ((unsigned int)half[1] << 16);
    }
    *(int4*)(Bg1 + (size_t)gid * 8) = make_int4(pk[0], pk[1], pk[2], pk[3]);
  } else if (bid < 746) {
    build_mid<7, 3>(w2, Bg2, (bid - 648) * 256 + tid);
  } else if (bid < 796) {
    build_mid<5, 2>(w3, Bg3, (bid - 746) * 256 + tid);
  } else {
    build_mid<3, 1>(w4, Bg4, (bid - 796) * 256 + tid);
  }
}

// ---------------- L1 helpers -------------------------------------------------
__device__ __forceinline__ void l1_loadB(const unsigned short* __restrict__ Bg, int kwkt,
                                         int chbase, int lane, bf16x8 (&B)[8]) {
#pragma unroll
  for (int c = 0; c < 2; ++c)
#pragma unroll
    for (int n = 0; n < 4; ++n)
      B[c * 4 + n] =
          *(const bf16x8*)(Bg + (((size_t)(kwkt * 8 + chbase + c) * 4 + n) << 9) + lane * 8);
}

__device__ __forceinline__ void l1_compute(const unsigned short* XTimg, int kwkt, int mhalf,
                                           int quad, int tl, const bf16x8 (&B)[8],
                                           f32x4 (&acc)[8][4]) {
  const int kw = kwkt / 9, kt = kwkt - kw * 9;
  const int t_i = tl + kt - 4;
  const bool tv = (unsigned)t_i < 16u;
#pragma unroll
  for (int m = 0; m < 8; ++m) {
    const int w_i = mhalf * 8 + m + kw - 4;
    const bool valid = tv && ((unsigned)w_i < 16u);
    const int row = valid ? (w_i * 16 + t_i) : 0;
    const unsigned int msk = valid ? 0xFFFFFFFFu : 0u;
    const int rh = row & 7;
    const int base = row * 64;
#pragma unroll
    for (int c = 0; c < 2; ++c) {
      const int unit = (c * 4 + quad) ^ rh;
      u32x4 a = *(const u32x4*)&XTimg[base + unit * 8];
      a.x &= msk; a.y &= msk; a.z &= msk; a.w &= msk;
      const bf16x8 af = __builtin_bit_cast(bf16x8, a);
#pragma unroll
      for (int n = 0; n < 4; ++n)
        acc[m][n] = __builtin_amdgcn_mfma_f32_16x16x32_bf16(af, B[c * 4 + n], acc[m][n], 0, 0, 0);
    }
  }
}

// ---------------- L1: 2 images/block, K-half/block, fp32 partials ------------
__global__ __launch_bounds__(256, 1) void conv_l1_mfma(const float* __restrict__ x,
                                                       const unsigned short* __restrict__ Bg,
                                                       float* __restrict__ P) {
  __shared__ __align__(16) unsigned short XT[2 * 256 * 64];  // 64 KB, swizzled
  const int bx = blockIdx.x;
  const int pair = bx >> 1, khalf = bx & 1;
  const int tid = threadIdx.x;
  const int lane = tid & 63, wave = tid >> 6;
  const int quad = lane >> 4, tl = lane & 15;
  const int img_l = wave >> 1, mhalf = wave & 1;
  f32x4 acc[8][4] = {};

  for (int qq = 0; qq < 2; ++qq) {
    const int q = khalf * 2 + qq;  // dh-quarter (64 dh values)
    __syncthreads();
    // stage both images' quarter, transposed + bf16 + swizzled
#pragma unroll
    for (int it = 0; it < 16; ++it) {
      const int idx = tid + it * 256;
      const int dhp = idx & 31;          // dh pair (2 dh per b32)
      const int w64 = (idx >> 5) & 63;   // wt/4
      const int img = idx >> 11;
      const float* src =
          x + (size_t)(pair * 2 + img) * 65536 + (size_t)(q * 64 + 2 * dhp) * 256 + w64 * 4;
      const float4 r0 = *(const float4*)src;
      const float4 r1 = *(const float4*)(src + 256);
      const float a0[4] = {r0.x, r0.y, r0.z, r0.w};
      const float a1[4] = {r1.x, r1.y, r1.z, r1.w};
      unsigned short* dst = XT + img * 16384;
      const int u0 = dhp >> 2, so = 2 * (dhp & 3);
#pragma unroll
      for (int j = 0; j < 4; ++j) {
        const int row = w64 * 4 + j;
        const unsigned int p = (unsigned int)f2bf(a0[j]) | ((unsigned int)f2bf(a1[j]) << 16);
        *(unsigned int*)&dst[row * 64 + ((u0 ^ (row & 7)) << 3) + so] = p;
      }
    }
    __syncthreads();
    const unsigned short* XTimg = XT + img_l * 16384;
    const int chbase = q * 2;
    bf16x8 B0[8], B1[8];
    l1_loadB(Bg, 0, chbase, lane, B0);
    int k = 0;
    while (true) {
      if (k + 1 < 81) l1_loadB(Bg, k + 1, chbase, lane, B1);
      l1_compute(XTimg, k, mhalf, quad, tl, B0, acc);
      if (++k >= 81) break;
      if (k + 1 < 81) l1_loadB(Bg, k + 1, chbase, lane, B0);
      l1_compute(XTimg, k, mhalf, quad, tl, B1, acc);
      if (++k >= 81) break;
    }
  }

  // store fp32 partial (no bias/relu).  D: n-col=lane&15, m-row=quad*4+reg
  float* Pb = P + (size_t)(khalf * 256 + pair * 2 + img_l) * 16384;
#pragma unroll
  for (int m = 0; m < 8; ++m)
#pragma unroll
    for (int n = 0; n < 4; ++n) {
      const int dh_o = n * 16 + tl;
      const int wt0 = (mhalf * 8 + m) * 16 + quad * 4;
      *(float4*)&Pb[(size_t)dh_o * 256 + wt0] = *(const float4*)&acc[m][n];
    }
}

// ---------------- L1 partial reduce: A = relu(P0 + P1 + bias) ----------------
__global__ __launch_bounds__(256) void reduce_l1(float* __restrict__ A,
                                                 const float* __restrict__ b1) {
  const float bias = b1[0];
  const int t = blockIdx.x * 256 + threadIdx.x;
  float4* a0 = (float4*)A;
  const float4* a1 = (const float4*)(A + (size_t)4194304);
#pragma unroll
  for (int i = 0; i < 16; ++i) {
    const int idx = t + i * 65536;
    float4 v = a0[idx];
    const float4 w = a1[idx];
    v.x = fmaxf(v.x + w.x + bias, 0.f);
    v.y = fmaxf(v.y + w.y + bias, 0.f);
    v.z = fmaxf(v.z + w.z + bias, 0.f);
    v.w = fmaxf(v.w + w.w + bias, 0.f);
    a0[idx] = v;
  }
}

// ---------------- mid layers: R4 structure (m=4/wave, 256 thr, in-place) -----
#define XTS 72

__device__ __forceinline__ void mid_mfma_block(const bf16x8 (&A)[8], const bf16x8 (&B)[8],
                                               f32x4 (&acc)[4][4]) {
#pragma unroll
  for (int c = 0; c < 2; ++c)
#pragma unroll
    for (int m = 0; m < 4; ++m)
#pragma unroll
      for (int n = 0; n < 4; ++n)
        acc[m][n] = __builtin_amdgcn_mfma_f32_16x16x32_bf16(A[c * 2 + m >= 0 ? c * 4 + m : 0],
                                                            B[c * 4 + n], acc[m][n], 0, 0, 0);
}

template <int KSZ, int PAD>
__device__ __forceinline__ void mid_load_tap(const unsigned short* XT,
                                             const unsigned short* __restrict__ Bg, int kwkt,
                                             int wave, int lane, int quad, int tl,
                                             bf16x8 (&A)[8], bf16x8 (&B)[8]) {
  const int kw = kwkt / KSZ, kt = kwkt - kw * KSZ;
  const int t_i = tl + kt - PAD;
  const bool tv = (unsigned)t_i < 16u;
  int ro[4];
#pragma unroll
  for (int m = 0; m < 4; ++m) {
    const int w_i = wave * 4 + m + kw - PAD;
    const bool v = tv && ((unsigned)w_i < 16u);
    const int row = v ? (w_i * 16 + t_i) : 256;  // row 256 = zeros
    ro[m] = row * XTS + quad * 8;
  }
#pragma unroll
  for (int c = 0; c < 2; ++c)
#pragma unroll
    for (int m = 0; m < 4; ++m)
      A[c * 4 + m] = *(const bf16x8*)&XT[ro[m] + c * 32];
#pragma unroll
  for (int c = 0; c < 2; ++c)
#pragma unroll
    for (int n = 0; n < 4; ++n)
      B[c * 4 + n] = *(const bf16x8*)(Bg + (((size_t)(kwkt * 2 + c) * 4 + n) << 9) + lane * 8);
}

template <int KSZ, int PAD, int NT>
__global__ __launch_bounds__(256) void conv_mid_mfma(float* __restrict__ y,
                                                     const unsigned short* __restrict__ Bg,
                                                     const float* __restrict__ bptr) {
  __shared__ __align__(16) unsigned short XT[257 * XTS];
  const int b = blockIdx.x;
  const int tid = threadIdx.x;
  const int lane = tid & 63, wave = tid >> 6;
  const int quad = lane >> 4, tl = lane & 15;
  float* yb = y + (size_t)b * 16384;
  f32x4 acc[4][4] = {};

  if (tid < 9) *(int4*)&XT[256 * XTS + tid * 8] = make_int4(0, 0, 0, 0);
#pragma unroll
  for (int it = 0; it < 8; ++it) {
    const int i = tid + it * 256;
    const int dhp = i >> 6, wtq = i & 63;
    const float4 r0 = *(const float4*)(yb + (size_t)(2 * dhp) * 256 + wtq * 4);
    const float4 r1 = *(const float4*)(yb + (size_t)(2 * dhp + 1) * 256 + wtq * 4);
    const float a0[4] = {r0.x, r0.y, r0.z, r0.w};
    const float a1[4] = {r1.x, r1.y, r1.z, r1.w};
#pragma unroll
    for (int j = 0; j < 4; ++j) {
      const unsigned int p = (unsigned int)f2bf(a0[j]) | ((unsigned int)f2bf(a1[j]) << 16);
      *(unsigned int*)&XT[(wtq * 4 + j) * XTS + dhp * 2] = p;
    }
  }
  __syncthreads();

  {
    bf16x8 A0[8], B0[8], A1[8], B1[8];
    mid_load_tap<KSZ, PAD>(XT, Bg, 0, wave, lane, quad, tl, A0, B0);
    int k = 0;
    while (true) {
      if (k + 1 < NT) mid_load_tap<KSZ, PAD>(XT, Bg, k + 1, wave, lane, quad, tl, A1, B1);
      {
#pragma unroll
        for (int c = 0; c < 2; ++c)
#pragma unroll
          for (int m = 0; m < 4; ++m)
#pragma unroll
            for (int n = 0; n < 4; ++n)
              acc[m][n] = __builtin_amdgcn_mfma_f32_16x16x32_bf16(A0[c * 4 + m], B0[c * 4 + n],
                                                                  acc[m][n], 0, 0, 0);
      }
      if (++k >= NT) break;
      if (k + 1 < NT) mid_load_tap<KSZ, PAD>(XT, Bg, k + 1, wave, lane, quad, tl, A0, B0);
      {
#pragma unroll
        for (int c = 0; c < 2; ++c)
#pragma unroll
          for (int m = 0; m < 4; ++m)
#pragma unroll
            for (int n = 0; n < 4; ++n)
              acc[m][n] = __builtin_amdgcn_mfma_f32_16x16x32_bf16(A1[c * 4 + m], B1[c * 4 + n],
                                                                  acc[m][n], 0, 0, 0);
      }
      if (++k >= NT) break;
    }
  }

  const float bias = bptr[0];
#pragma unroll
  for (int m = 0; m < 4; ++m)
#pragma unroll
    for (int n = 0; n < 4; ++n) {
      const int dh_o = n * 16 + tl;
      const int wt0 = wave * 64 + m * 16 + quad * 4;
      float4 v;
      v.x = fmaxf(acc[m][n][0] + bias, 0.f);
      v.y = fmaxf(acc[m][n][1] + bias, 0.f);
      v.z = fmaxf(acc[m][n][2] + bias, 0.f);
      v.w = fmaxf(acc[m][n][3] + bias, 0.f);
      *(float4*)&yb[(size_t)dh_o * 256 + wt0] = v;
    }
}

// ---------------- L5 ---------------------------------------------------------
__global__ __launch_bounds__(256) void conv_l5(const float* __restrict__ x,
                                               const float* __restrict__ w5,
                                               const float* __restrict__ b5,
                                               float* __restrict__ out) {
  const int b = blockIdx.x;
  const int tid = threadIdx.x;
  const float* xb = x + (size_t)b * 16384 + tid;
  float s = b5[0];
#pragma unroll
  for (int k = 0; k < 64; ++k) s += xb[k * 256] * w5[k];
  out[(size_t)b * 256 + tid] = 1.f / (1.f + expf(-s));
}

extern "C" void kernel_launch(void* const* d_in, const int* in_sizes, int n_in,
                              void* d_out, int out_size, void* d_ws, size_t ws_size,
                              hipStream_t stream) {
  const float* corr = (const float*)d_in[0];
  const float* w1 = (const float*)d_in[1];
  const float* b1 = (const float*)d_in[2];
  const float* w2 = (const float*)d_in[3];
  const float* b2 = (const float*)d_in[4];
  const float* w3 = (const float*)d_in[5];
  const float* b3 = (const float*)d_in[6];
  const float* w4 = (const float*)d_in[7];
  const float* b4 = (const float*)d_in[8];
  const float* w5 = (const float*)d_in[9];
  const float* b5 = (const float*)d_in[10];

  // ws layout: [0,16M) act A == L1 partial khalf0; [16M,32M) L1 partial khalf1;
  // [32M, ~35.3M) B matrices.
  float* A = (float*)d_ws;
  unsigned short* Bg1 = (unsigned short*)((char*)d_ws + (32u << 20));
  unsigned short* Bg2 = Bg1 + (size_t)81 * 8 * 4 * 64 * 8;
  unsigned short* Bg3 = Bg2 + (size_t)49 * 2 * 4 * 64 * 8;
  unsigned short* Bg4 = Bg3 + (size_t)25 * 2 * 4 * 64 * 8;

  build_all<<<814, 256, 0, stream>>>(w1, w2, w3, w4, Bg1, Bg2, Bg3, Bg4);
  conv_l1_mfma<<<256, 256, 0, stream>>>(corr, Bg1, A);
  reduce_l1<<<256, 256, 0, stream>>>(A, b1);
  conv_mid_mfma<7, 3, 49><<<256, 256, 0, stream>>>(A, Bg2, b2);
  conv_mid_mfma<5, 2, 25><<<256, 256, 0, stream>>>(A, Bg3, b3);
  conv_mid_mfma<3, 1, 9><<<256, 256, 0, stream>>>(A, Bg4, b4);
  conv_l5<<<256, 256, 0, stream>>>(A, w5, b5, (float*)d_out);
}

// Round 7
// 349.093 us; speedup vs baseline: 1.0703x; 1.0703x over previous
//
#include <hip/hip_runtime.h>
#include <math.h>

// Net (per image b of 256):  x: (dh=256, wt=256), dh=d*16+h, wt=w*16+t
//  L1: w1 (17,17,9,9) pad4 -> (dh_o=64, wt=256) relu      [MFMA, 81 taps, K=256]
//  L2: w2 (7,7,7,7)  pad3 -> same, relu                   [MFMA, 49 taps, K=64]
//  L3: w3 (5,5,5,5)  pad2 -> relu
//  L4: w4 (3,3,3,3)  pad1 -> relu
//  L5: w5 (8,8)      -> sigmoid -> out (256,16,16)
//
// R7: (1) conv_l1 = R4 structure (m=4/wave, 4 waves, 37KB LDS) + K-half split
//     -> grid 512 = 2 blocks/CU = 2 waves/SIMD. Per-wave operand economics
//     unchanged vs R4 (best measured); only co-residency doubles. fp32
//     partials + reduce_l1.
//     (2) L2..L5 fused into one persistent kernel: tap loops unchanged, but
//     inter-layer activations stay in LDS (epilogue re-transposes acc into XT
//     as bf16 with bias+relu); L5 reads XT. Kills 3 launches + 96MB HBM.

typedef short bf16x8 __attribute__((ext_vector_type(8)));
typedef float f32x4 __attribute__((ext_vector_type(4)));
typedef unsigned int u32x4 __attribute__((ext_vector_type(4)));

#define XTS 72  // XT row stride in shorts (16B-aligned rows; start banks spread)

__device__ __forceinline__ unsigned short f2bf(float f) {
  unsigned int u = __float_as_uint(f);
  u += 0x7fffu + ((u >> 16) & 1u);  // RNE
  return (unsigned short)(u >> 16);
}

// ---------------- B-matrix precompute (layouts as R4) ------------------------
template <int KSZ, int PAD>
__device__ __forceinline__ void build_mid(const float* __restrict__ w,
                                          unsigned short* __restrict__ Bg, int gid) {
  const int lane = gid & 63;
  const int n_tile = (gid >> 6) & 3;
  const int chunk = (gid >> 8) & 1;
  const int tap = gid >> 9;
  const int kw = tap / KSZ, kt = tap - kw * KSZ;
  const int dh_o = n_tile * 16 + (lane & 15);
  const int d_o = dh_o >> 3, h_o = dh_o & 7;
  const int kbase = chunk * 32 + (lane >> 4) * 8;
  unsigned int pk[4];
#pragma unroll
  for (int p = 0; p < 4; ++p) {
    unsigned short half[2];
#pragma unroll
    for (int s = 0; s < 2; ++s) {
      const int k = kbase + p * 2 + s;
      const int d_i = k >> 3, h_i = k & 7;
      const int kd = d_i - d_o + PAD, kh = h_i - h_o + PAD;
      float v = 0.f;
      if (kd >= 0 && kd < KSZ && kh >= 0 && kh < KSZ)
        v = w[((kd * KSZ + kh) * KSZ + kw) * KSZ + kt];
      half[s] = f2bf(v);
    }
    pk[p] = (unsigned int)half[0] | ((unsigned int)half[1] << 16);
  }
  *(int4*)(Bg + (size_t)gid * 8) = make_int4(pk[0], pk[1], pk[2], pk[3]);
}

__global__ __launch_bounds__(256) void build_all(const float* __restrict__ w1,
                                                 const float* __restrict__ w2,
                                                 const float* __restrict__ w3,
                                                 const float* __restrict__ w4,
                                                 unsigned short* __restrict__ Bg1,
                                                 unsigned short* __restrict__ Bg2,
                                                 unsigned short* __restrict__ Bg3,
                                                 unsigned short* __restrict__ Bg4) {
  const int bid = blockIdx.x, tid = threadIdx.x;
  if (bid < 648) {  // L1: 81 taps * 8 chunks * 4 ntiles * 64 lanes
    const int gid = bid * 256 + tid;
    const int lane = gid & 63;
    const int n_tile = (gid >> 6) & 3;
    const int chunk = (gid >> 8) & 7;
    const int kwkt = gid >> 11;
    const int kw = kwkt / 9, kt = kwkt - kw * 9;
    const int dh_o = n_tile * 16 + (lane & 15);
    const int d_o = dh_o >> 3, h_o = dh_o & 7;
    const int kbase = chunk * 32 + (lane >> 4) * 8;
    unsigned int pk[4];
#pragma unroll
    for (int p = 0; p < 4; ++p) {
      unsigned short half[2];
#pragma unroll
      for (int s = 0; s < 2; ++s) {
        const int k = kbase + p * 2 + s;
        const int d_i = k >> 4, h_i = k & 15;
        const int kd = d_i - d_o + 4, kh = h_i - h_o + 4;
        float v = 0.f;
        if (kd >= 0 && kd < 17 && kh >= 0 && kh < 17)
          v = w1[((kd * 17 + kh) * 9 + kw) * 9 + kt];
        half[s] = f2bf(v);
      }
      pk[p] = (unsigned int)half[0] | ((unsigned int)half[1] << 16);
    }
    *(int4*)(Bg1 + (size_t)gid * 8) = make_int4(pk[0], pk[1], pk[2], pk[3]);
  } else if (bid < 746) {
    build_mid<7, 3>(w2, Bg2, (bid - 648) * 256 + tid);
  } else if (bid < 796) {
    build_mid<5, 2>(w3, Bg3, (bid - 746) * 256 + tid);
  } else {
    build_mid<3, 1>(w4, Bg4, (bid - 796) * 256 + tid);
  }
}

// ---------------- L1 load/compute (m=4/wave, CHTOT=8) ------------------------
__device__ __forceinline__ void l1_load_tap(const unsigned short* XT,
                                            const unsigned short* __restrict__ Bg,
                                            int chbase, int kwkt, int wave, int lane,
                                            int quad, int tl, bf16x8 (&A)[8], bf16x8 (&B)[8]) {
  const int kw = kwkt / 9, kt = kwkt - kw * 9;
  const int t_i = tl + kt - 4;
  const bool tv = (unsigned)t_i < 16u;
  int ro[4];
#pragma unroll
  for (int m = 0; m < 4; ++m) {
    const int w_i = wave * 4 + m + kw - 4;
    const bool v = tv && ((unsigned)w_i < 16u);
    const int row = v ? (w_i * 16 + t_i) : 256;  // row 256 = zeros
    ro[m] = row * XTS + quad * 8;
  }
#pragma unroll
  for (int c = 0; c < 2; ++c)
#pragma unroll
    for (int m = 0; m < 4; ++m)
      A[c * 4 + m] = *(const bf16x8*)&XT[ro[m] + c * 32];
#pragma unroll
  for (int c = 0; c < 2; ++c)
#pragma unroll
    for (int n = 0; n < 4; ++n)
      B[c * 4 + n] = *(const bf16x8*)(Bg + (((size_t)(kwkt * 8 + chbase + c) * 4 + n) << 9) +
                                      lane * 8);
}

__device__ __forceinline__ void mfma16(const bf16x8 (&A)[8], const bf16x8 (&B)[8],
                                       f32x4 (&acc)[4][4]) {
#pragma unroll
  for (int c = 0; c < 2; ++c)
#pragma unroll
    for (int m = 0; m < 4; ++m)
#pragma unroll
      for (int n = 0; n < 4; ++n)
        acc[m][n] = __builtin_amdgcn_mfma_f32_16x16x32_bf16(A[c * 4 + m], B[c * 4 + n],
                                                            acc[m][n], 0, 0, 0);
}

// ---------------- conv_l1: grid 512 = image x khalf, fp32 partials -----------
__global__ __launch_bounds__(256, 2) void conv_l1_mfma(const float* __restrict__ x,
                                                       const unsigned short* __restrict__ Bg,
                                                       float* __restrict__ P) {
  __shared__ __align__(16) unsigned short XT[257 * XTS];  // 37 KB
  const int bx = blockIdx.x;
  const int b = bx >> 1, khalf = bx & 1;
  const int tid = threadIdx.x;
  const int lane = tid & 63, wave = tid >> 6;
  const int quad = lane >> 4, tl = lane & 15;
  const float* xb = x + (size_t)b * 65536;
  f32x4 acc[4][4] = {};

  if (tid < 9) *(int4*)&XT[256 * XTS + tid * 8] = make_int4(0, 0, 0, 0);

  for (int qq = 0; qq < 2; ++qq) {
    const int q = khalf * 2 + qq;  // dh-quarter
    __syncthreads();
#pragma unroll
    for (int it = 0; it < 8; ++it) {
      const int i = tid + it * 256;
      const int dhp = i >> 6, wtq = i & 63;
      const float4 r0 = *(const float4*)(xb + (size_t)(q * 64 + 2 * dhp) * 256 + wtq * 4);
      const float4 r1 = *(const float4*)(xb + (size_t)(q * 64 + 2 * dhp + 1) * 256 + wtq * 4);
      const float a0[4] = {r0.x, r0.y, r0.z, r0.w};
      const float a1[4] = {r1.x, r1.y, r1.z, r1.w};
#pragma unroll
      for (int j = 0; j < 4; ++j) {
        const unsigned int p = (unsigned int)f2bf(a0[j]) | ((unsigned int)f2bf(a1[j]) << 16);
        *(unsigned int*)&XT[(wtq * 4 + j) * XTS + dhp * 2] = p;
      }
    }
    __syncthreads();
    const int chbase = q * 2;
    {
      bf16x8 A0[8], B0[8], A1[8], B1[8];
      l1_load_tap(XT, Bg, chbase, 0, wave, lane, quad, tl, A0, B0);
      int k = 0;
      while (true) {
        if (k + 1 < 81) l1_load_tap(XT, Bg, chbase, k + 1, wave, lane, quad, tl, A1, B1);
        mfma16(A0, B0, acc);
        if (++k >= 81) break;
        if (k + 1 < 81) l1_load_tap(XT, Bg, chbase, k + 1, wave, lane, quad, tl, A0, B0);
        mfma16(A1, B1, acc);
        if (++k >= 81) break;
      }
    }
  }

  // store fp32 partial (no bias/relu).  D: col=lane&15 (dh_o), row=quad*4+reg (wt)
  float* Pb = P + (size_t)(khalf * 256 + b) * 16384;
#pragma unroll
  for (int m = 0; m < 4; ++m)
#pragma unroll
    for (int n = 0; n < 4; ++n) {
      const int dh_o = n * 16 + tl;
      const int wt0 = wave * 64 + m * 16 + quad * 4;
      *(float4*)&Pb[(size_t)dh_o * 256 + wt0] = *(const float4*)&acc[m][n];
    }
}

// ---------------- L1 partial reduce: A = relu(P0 + P1 + bias) ----------------
__global__ __launch_bounds__(256) void reduce_l1(float* __restrict__ A,
                                                 const float* __restrict__ b1) {
  const float bias = b1[0];
  const int t = blockIdx.x * 256 + threadIdx.x;
  float4* a0 = (float4*)A;
  const float4* a1 = (const float4*)(A + (size_t)4194304);
#pragma unroll
  for (int i = 0; i < 16; ++i) {
    const int idx = t + i * 65536;
    float4 v = a0[idx];
    const float4 w = a1[idx];
    v.x = fmaxf(v.x + w.x + bias, 0.f);
    v.y = fmaxf(v.y + w.y + bias, 0.f);
    v.z = fmaxf(v.z + w.z + bias, 0.f);
    v.w = fmaxf(v.w + w.w + bias, 0.f);
    a0[idx] = v;
  }
}

// ---------------- fused tail: L2 -> L3 -> L4 -> L5, one block per image ------
template <int KSZ, int PAD>
__device__ __forceinline__ void mid_load_tap(const unsigned short* XT,
                                             const unsigned short* __restrict__ Bg, int kwkt,
                                             int wave, int lane, int quad, int tl,
                                             bf16x8 (&A)[8], bf16x8 (&B)[8]) {
  const int kw = kwkt / KSZ, kt = kwkt - kw * KSZ;
  const int t_i = tl + kt - PAD;
  const bool tv = (unsigned)t_i < 16u;
  int ro[4];
#pragma unroll
  for (int m = 0; m < 4; ++m) {
    const int w_i = wave * 4 + m + kw - PAD;
    const bool v = tv && ((unsigned)w_i < 16u);
    const int row = v ? (w_i * 16 + t_i) : 256;  // row 256 = zeros
    ro[m] = row * XTS + quad * 8;
  }
#pragma unroll
  for (int c = 0; c < 2; ++c)
#pragma unroll
    for (int m = 0; m < 4; ++m)
      A[c * 4 + m] = *(const bf16x8*)&XT[ro[m] + c * 32];
#pragma unroll
  for (int c = 0; c < 2; ++c)
#pragma unroll
    for (int n = 0; n < 4; ++n)
      B[c * 4 + n] = *(const bf16x8*)(Bg + (((size_t)(kwkt * 2 + c) * 4 + n) << 9) + lane * 8);
}

template <int KSZ, int PAD, int NT>
__device__ __forceinline__ void run_layer(unsigned short* XT,
                                          const unsigned short* __restrict__ Bg,
                                          const float bias, int wave, int lane, int quad,
                                          int tl) {
  f32x4 acc[4][4] = {};
  {
    bf16x8 A0[8], B0[8], A1[8], B1[8];
    mid_load_tap<KSZ, PAD>(XT, Bg, 0, wave, lane, quad, tl, A0, B0);
    int k = 0;
    while (true) {
      if (k + 1 < NT) mid_load_tap<KSZ, PAD>(XT, Bg, k + 1, wave, lane, quad, tl, A1, B1);
      mfma16(A0, B0, acc);
      if (++k >= NT) break;
      if (k + 1 < NT) mid_load_tap<KSZ, PAD>(XT, Bg, k + 1, wave, lane, quad, tl, A0, B0);
      mfma16(A1, B1, acc);
      if (++k >= NT) break;
    }
  }
  __syncthreads();  // all XT reads for this layer complete
  // epilogue: bias+relu+bf16, re-transpose into XT[wt][dh]
#pragma unroll
  for (int m = 0; m < 4; ++m)
#pragma unroll
    for (int n = 0; n < 4; ++n) {
      const int col = n * 16 + tl;
      const int wt0 = wave * 64 + m * 16 + quad * 4;
#pragma unroll
      for (int j = 0; j < 4; ++j)
        XT[(wt0 + j) * XTS + col] = f2bf(fmaxf(acc[m][n][j] + bias, 0.f));
    }
  __syncthreads();  // XT updated for next layer
}

__global__ __launch_bounds__(256) void tail_fused(const float* __restrict__ A,
                                                  const unsigned short* __restrict__ Bg2,
                                                  const unsigned short* __restrict__ Bg3,
                                                  const unsigned short* __restrict__ Bg4,
                                                  const float* __restrict__ b2,
                                                  const float* __restrict__ b3,
                                                  const float* __restrict__ b4,
                                                  const float* __restrict__ w5,
                                                  const float* __restrict__ b5,
                                                  float* __restrict__ out) {
  __shared__ __align__(16) unsigned short XT[257 * XTS];  // 37 KB
  const int b = blockIdx.x;
  const int tid = threadIdx.x;
  const int lane = tid & 63, wave = tid >> 6;
  const int quad = lane >> 4, tl = lane & 15;
  const float* yb = A + (size_t)b * 16384;

  if (tid < 9) *(int4*)&XT[256 * XTS + tid * 8] = make_int4(0, 0, 0, 0);
#pragma unroll
  for (int it = 0; it < 8; ++it) {
    const int i = tid + it * 256;
    const int dhp = i >> 6, wtq = i & 63;
    const float4 r0 = *(const float4*)(yb + (size_t)(2 * dhp) * 256 + wtq * 4);
    const float4 r1 = *(const float4*)(yb + (size_t)(2 * dhp + 1) * 256 + wtq * 4);
    const float a0[4] = {r0.x, r0.y, r0.z, r0.w};
    const float a1[4] = {r1.x, r1.y, r1.z, r1.w};
#pragma unroll
    for (int j = 0; j < 4; ++j) {
      const unsigned int p = (unsigned int)f2bf(a0[j]) | ((unsigned int)f2bf(a1[j]) << 16);
      *(unsigned int*)&XT[(wtq * 4 + j) * XTS + dhp * 2] = p;
    }
  }
  __syncthreads();

  run_layer<7, 3, 49>(XT, Bg2, b2[0], wave, lane, quad, tl);
  run_layer<5, 2, 25>(XT, Bg3, b3[0], wave, lane, quad, tl);
  run_layer<3, 1, 9>(XT, Bg4, b4[0], wave, lane, quad, tl);

  // L5: out[wt] = sigmoid(b5 + sum_dh w5[dh] * y4[wt][dh]); XT rows are wt
  const int wt = tid;
  float s = b5[0];
  const unsigned short* row = &XT[wt * XTS];
#pragma unroll
  for (int k8 = 0; k8 < 8; ++k8) {
    const u32x4 v = *(const u32x4*)&row[k8 * 8];
    const unsigned int uu[4] = {(unsigned int)v.x, (unsigned int)v.y, (unsigned int)v.z,
                                (unsigned int)v.w};
#pragma unroll
    for (int p = 0; p < 4; ++p) {
      const float lo = __uint_as_float(uu[p] << 16);
      const float hi = __uint_as_float(uu[p] & 0xFFFF0000u);
      s += lo * w5[k8 * 8 + p * 2] + hi * w5[k8 * 8 + p * 2 + 1];
    }
  }
  out[(size_t)b * 256 + wt] = 1.f / (1.f + expf(-s));
}

extern "C" void kernel_launch(void* const* d_in, const int* in_sizes, int n_in,
                              void* d_out, int out_size, void* d_ws, size_t ws_size,
                              hipStream_t stream) {
  const float* corr = (const float*)d_in[0];
  const float* w1 = (const float*)d_in[1];
  const float* b1 = (const float*)d_in[2];
  const float* w2 = (const float*)d_in[3];
  const float* b2 = (const float*)d_in[4];
  const float* w3 = (const float*)d_in[5];
  const float* b3 = (const float*)d_in[6];
  const float* w4 = (const float*)d_in[7];
  const float* b4 = (const float*)d_in[8];
  const float* w5 = (const float*)d_in[9];
  const float* b5 = (const float*)d_in[10];

  // ws: [0,16M) act A == L1 partial khalf0; [16M,32M) partial khalf1; [32M,..) B mats
  float* A = (float*)d_ws;
  unsigned short* Bg1 = (unsigned short*)((char*)d_ws + (32u << 20));
  unsigned short* Bg2 = Bg1 + (size_t)81 * 8 * 4 * 64 * 8;
  unsigned short* Bg3 = Bg2 + (size_t)49 * 2 * 4 * 64 * 8;
  unsigned short* Bg4 = Bg3 + (size_t)25 * 2 * 4 * 64 * 8;

  build_all<<<814, 256, 0, stream>>>(w1, w2, w3, w4, Bg1, Bg2, Bg3, Bg4);
  conv_l1_mfma<<<512, 256, 0, stream>>>(corr, Bg1, A);
  reduce_l1<<<256, 256, 0, stream>>>(A, b1);
  tail_fused<<<256, 256, 0, stream>>>(A, Bg2, Bg3, Bg4, b2, b3, b4, w5, b5, (float*)d_out);
}

// Round 8
// 299.567 us; speedup vs baseline: 1.2472x; 1.1653x over previous
//
#include <hip/hip_runtime.h>
#include <math.h>

// Net (per image b of 256):  x: (dh=256, wt=256), dh=d*16+h, wt=w*16+t
//  L1: w1 (17,17,9,9) pad4 -> (dh_o=64, wt=256) relu      [MFMA, 81 taps, K=256]
//  L2: w2 (7,7,7,7)  pad3 -> same, relu                   [MFMA, 49 taps, K=64]
//  L3: w3 (5,5,5,5)  pad2 -> relu
//  L4: w4 (3,3,3,3)  pad1 -> relu
//  L5: w5 (8,8)      -> sigmoid -> out (256,16,16)
//
// R8: (1) conv_l1 = R7 khalf-split (grid 512 -> 2 blocks/CU) but WITHOUT the
//     __launch_bounds__(256,2) cap that forced VGPR 148->128 and spilled the
//     pipeline regs (R7: WRITE_SIZE 58MB vs 32MB expected = scratch stores).
//     (2) tail_fused now 512 thr = 8 waves in a 4(m) x 2(n) wave grid
//     (m=4, n=2 tiles/wave) -> 2 waves/SIMD without increasing B traffic/work.
//     (3) reduce_l1 folded into tail staging: XT = bf16(relu(P0+P1+b1)).

typedef short bf16x8 __attribute__((ext_vector_type(8)));
typedef float f32x4 __attribute__((ext_vector_type(4)));
typedef unsigned int u32x4 __attribute__((ext_vector_type(4)));

#define XTS 72  // XT row stride in shorts (16B-aligned rows; start banks spread)

__device__ __forceinline__ unsigned short f2bf(float f) {
  unsigned int u = __float_as_uint(f);
  u += 0x7fffu + ((u >> 16) & 1u);  // RNE
  return (unsigned short)(u >> 16);
}

// ---------------- B-matrix precompute (layouts as R4) ------------------------
template <int KSZ, int PAD>
__device__ __forceinline__ void build_mid(const float* __restrict__ w,
                                          unsigned short* __restrict__ Bg, int gid) {
  const int lane = gid & 63;
  const int n_tile = (gid >> 6) & 3;
  const int chunk = (gid >> 8) & 1;
  const int tap = gid >> 9;
  const int kw = tap / KSZ, kt = tap - kw * KSZ;
  const int dh_o = n_tile * 16 + (lane & 15);
  const int d_o = dh_o >> 3, h_o = dh_o & 7;
  const int kbase = chunk * 32 + (lane >> 4) * 8;
  unsigned int pk[4];
#pragma unroll
  for (int p = 0; p < 4; ++p) {
    unsigned short half[2];
#pragma unroll
    for (int s = 0; s < 2; ++s) {
      const int k = kbase + p * 2 + s;
      const int d_i = k >> 3, h_i = k & 7;
      const int kd = d_i - d_o + PAD, kh = h_i - h_o + PAD;
      float v = 0.f;
      if (kd >= 0 && kd < KSZ && kh >= 0 && kh < KSZ)
        v = w[((kd * KSZ + kh) * KSZ + kw) * KSZ + kt];
      half[s] = f2bf(v);
    }
    pk[p] = (unsigned int)half[0] | ((unsigned int)half[1] << 16);
  }
  *(int4*)(Bg + (size_t)gid * 8) = make_int4(pk[0], pk[1], pk[2], pk[3]);
}

__global__ __launch_bounds__(256) void build_all(const float* __restrict__ w1,
                                                 const float* __restrict__ w2,
                                                 const float* __restrict__ w3,
                                                 const float* __restrict__ w4,
                                                 unsigned short* __restrict__ Bg1,
                                                 unsigned short* __restrict__ Bg2,
                                                 unsigned short* __restrict__ Bg3,
                                                 unsigned short* __restrict__ Bg4) {
  const int bid = blockIdx.x, tid = threadIdx.x;
  if (bid < 648) {  // L1: 81 taps * 8 chunks * 4 ntiles * 64 lanes
    const int gid = bid * 256 + tid;
    const int lane = gid & 63;
    const int n_tile = (gid >> 6) & 3;
    const int chunk = (gid >> 8) & 7;
    const int kwkt = gid >> 11;
    const int kw = kwkt / 9, kt = kwkt - kw * 9;
    const int dh_o = n_tile * 16 + (lane & 15);
    const int d_o = dh_o >> 3, h_o = dh_o & 7;
    const int kbase = chunk * 32 + (lane >> 4) * 8;
    unsigned int pk[4];
#pragma unroll
    for (int p = 0; p < 4; ++p) {
      unsigned short half[2];
#pragma unroll
      for (int s = 0; s < 2; ++s) {
        const int k = kbase + p * 2 + s;
        const int d_i = k >> 4, h_i = k & 15;
        const int kd = d_i - d_o + 4, kh = h_i - h_o + 4;
        float v = 0.f;
        if (kd >= 0 && kd < 17 && kh >= 0 && kh < 17)
          v = w1[((kd * 17 + kh) * 9 + kw) * 9 + kt];
        half[s] = f2bf(v);
      }
      pk[p] = (unsigned int)half[0] | ((unsigned int)half[1] << 16);
    }
    *(int4*)(Bg1 + (size_t)gid * 8) = make_int4(pk[0], pk[1], pk[2], pk[3]);
  } else if (bid < 746) {
    build_mid<7, 3>(w2, Bg2, (bid - 648) * 256 + tid);
  } else if (bid < 796) {
    build_mid<5, 2>(w3, Bg3, (bid - 746) * 256 + tid);
  } else {
    build_mid<3, 1>(w4, Bg4, (bid - 796) * 256 + tid);
  }
}

// ---------------- L1 load/compute (m=4/wave, CHTOT=8) ------------------------
__device__ __forceinline__ void l1_load_tap(const unsigned short* XT,
                                            const unsigned short* __restrict__ Bg,
                                            int chbase, int kwkt, int wave, int lane,
                                            int quad, int tl, bf16x8 (&A)[8], bf16x8 (&B)[8]) {
  const int kw = kwkt / 9, kt = kwkt - kw * 9;
  const int t_i = tl + kt - 4;
  const bool tv = (unsigned)t_i < 16u;
  int ro[4];
#pragma unroll
  for (int m = 0; m < 4; ++m) {
    const int w_i = wave * 4 + m + kw - 4;
    const bool v = tv && ((unsigned)w_i < 16u);
    const int row = v ? (w_i * 16 + t_i) : 256;  // row 256 = zeros
    ro[m] = row * XTS + quad * 8;
  }
#pragma unroll
  for (int c = 0; c < 2; ++c)
#pragma unroll
    for (int m = 0; m < 4; ++m)
      A[c * 4 + m] = *(const bf16x8*)&XT[ro[m] + c * 32];
#pragma unroll
  for (int c = 0; c < 2; ++c)
#pragma unroll
    for (int n = 0; n < 4; ++n)
      B[c * 4 + n] = *(const bf16x8*)(Bg + (((size_t)(kwkt * 8 + chbase + c) * 4 + n) << 9) +
                                      lane * 8);
}

__device__ __forceinline__ void mfma16(const bf16x8 (&A)[8], const bf16x8 (&B)[8],
                                       f32x4 (&acc)[4][4]) {
#pragma unroll
  for (int c = 0; c < 2; ++c)
#pragma unroll
    for (int m = 0; m < 4; ++m)
#pragma unroll
      for (int n = 0; n < 4; ++n)
        acc[m][n] = __builtin_amdgcn_mfma_f32_16x16x32_bf16(A[c * 4 + m], B[c * 4 + n],
                                                            acc[m][n], 0, 0, 0);
}

// ---------------- conv_l1: grid 512 = image x khalf, fp32 partials -----------
__global__ __launch_bounds__(256) void conv_l1_mfma(const float* __restrict__ x,
                                                    const unsigned short* __restrict__ Bg,
                                                    float* __restrict__ P) {
  __shared__ __align__(16) unsigned short XT[257 * XTS];  // 37 KB
  const int bx = blockIdx.x;
  const int b = bx >> 1, khalf = bx & 1;
  const int tid = threadIdx.x;
  const int lane = tid & 63, wave = tid >> 6;
  const int quad = lane >> 4, tl = lane & 15;
  const float* xb = x + (size_t)b * 65536;
  f32x4 acc[4][4] = {};

  if (tid < 9) *(int4*)&XT[256 * XTS + tid * 8] = make_int4(0, 0, 0, 0);

  for (int qq = 0; qq < 2; ++qq) {
    const int q = khalf * 2 + qq;  // dh-quarter
    __syncthreads();
#pragma unroll
    for (int it = 0; it < 8; ++it) {
      const int i = tid + it * 256;
      const int dhp = i >> 6, wtq = i & 63;
      const float4 r0 = *(const float4*)(xb + (size_t)(q * 64 + 2 * dhp) * 256 + wtq * 4);
      const float4 r1 = *(const float4*)(xb + (size_t)(q * 64 + 2 * dhp + 1) * 256 + wtq * 4);
      const float a0[4] = {r0.x, r0.y, r0.z, r0.w};
      const float a1[4] = {r1.x, r1.y, r1.z, r1.w};
#pragma unroll
      for (int j = 0; j < 4; ++j) {
        const unsigned int p = (unsigned int)f2bf(a0[j]) | ((unsigned int)f2bf(a1[j]) << 16);
        *(unsigned int*)&XT[(wtq * 4 + j) * XTS + dhp * 2] = p;
      }
    }
    __syncthreads();
    const int chbase = q * 2;
    {
      bf16x8 A0[8], B0[8], A1[8], B1[8];
      l1_load_tap(XT, Bg, chbase, 0, wave, lane, quad, tl, A0, B0);
      int k = 0;
      while (true) {
        if (k + 1 < 81) l1_load_tap(XT, Bg, chbase, k + 1, wave, lane, quad, tl, A1, B1);
        mfma16(A0, B0, acc);
        if (++k >= 81) break;
        if (k + 1 < 81) l1_load_tap(XT, Bg, chbase, k + 1, wave, lane, quad, tl, A0, B0);
        mfma16(A1, B1, acc);
        if (++k >= 81) break;
      }
    }
  }

  // store fp32 partial (no bias/relu).  D: col=lane&15 (dh_o), row=quad*4+reg (wt)
  float* Pb = P + (size_t)(khalf * 256 + b) * 16384;
#pragma unroll
  for (int m = 0; m < 4; ++m)
#pragma unroll
    for (int n = 0; n < 4; ++n) {
      const int dh_o = n * 16 + tl;
      const int wt0 = wave * 64 + m * 16 + quad * 4;
      *(float4*)&Pb[(size_t)dh_o * 256 + wt0] = *(const float4*)&acc[m][n];
    }
}

// ---------------- fused tail: L2 -> L3 -> L4 -> L5, 512 thr, m4 x n2 waves ---
template <int KSZ, int PAD>
__device__ __forceinline__ void tail_load_tap(const unsigned short* XT,
                                              const unsigned short* __restrict__ Bg, int kwkt,
                                              int mw, int nh, int lane, int quad, int tl,
                                              bf16x8 (&A)[8], bf16x8 (&B)[4]) {
  const int kw = kwkt / KSZ, kt = kwkt - kw * KSZ;
  const int t_i = tl + kt - PAD;
  const bool tv = (unsigned)t_i < 16u;
  int ro[4];
#pragma unroll
  for (int m = 0; m < 4; ++m) {
    const int w_i = mw * 4 + m + kw - PAD;
    const bool v = tv && ((unsigned)w_i < 16u);
    const int row = v ? (w_i * 16 + t_i) : 256;  // row 256 = zeros
    ro[m] = row * XTS + quad * 8;
  }
#pragma unroll
  for (int c = 0; c < 2; ++c)
#pragma unroll
    for (int m = 0; m < 4; ++m)
      A[c * 4 + m] = *(const bf16x8*)&XT[ro[m] + c * 32];
#pragma unroll
  for (int c = 0; c < 2; ++c)
#pragma unroll
    for (int n = 0; n < 2; ++n)
      B[c * 2 + n] =
          *(const bf16x8*)(Bg + (((size_t)(kwkt * 2 + c) * 4 + (nh * 2 + n)) << 9) + lane * 8);
}

__device__ __forceinline__ void mfma8(const bf16x8 (&A)[8], const bf16x8 (&B)[4],
                                      f32x4 (&acc)[4][2]) {
#pragma unroll
  for (int c = 0; c < 2; ++c)
#pragma unroll
    for (int m = 0; m < 4; ++m)
#pragma unroll
      for (int n = 0; n < 2; ++n)
        acc[m][n] = __builtin_amdgcn_mfma_f32_16x16x32_bf16(A[c * 4 + m], B[c * 2 + n],
                                                            acc[m][n], 0, 0, 0);
}

template <int KSZ, int PAD, int NT>
__device__ __forceinline__ void run_layer(unsigned short* XT,
                                          const unsigned short* __restrict__ Bg,
                                          const float bias, int mw, int nh, int lane,
                                          int quad, int tl) {
  f32x4 acc[4][2] = {};
  {
    bf16x8 A0[8], B0[4], A1[8], B1[4];
    tail_load_tap<KSZ, PAD>(XT, Bg, 0, mw, nh, lane, quad, tl, A0, B0);
    int k = 0;
    while (true) {
      if (k + 1 < NT) tail_load_tap<KSZ, PAD>(XT, Bg, k + 1, mw, nh, lane, quad, tl, A1, B1);
      mfma8(A0, B0, acc);
      if (++k >= NT) break;
      if (k + 1 < NT) tail_load_tap<KSZ, PAD>(XT, Bg, k + 1, mw, nh, lane, quad, tl, A0, B0);
      mfma8(A1, B1, acc);
      if (++k >= NT) break;
    }
  }
  __syncthreads();  // all XT reads for this layer complete
  // epilogue: bias+relu+bf16, re-transpose into XT[wt][dh]
#pragma unroll
  for (int m = 0; m < 4; ++m)
#pragma unroll
    for (int n = 0; n < 2; ++n) {
      const int col = (nh * 2 + n) * 16 + tl;
      const int wt0 = mw * 64 + m * 16 + quad * 4;
#pragma unroll
      for (int j = 0; j < 4; ++j)
        XT[(wt0 + j) * XTS + col] = f2bf(fmaxf(acc[m][n][j] + bias, 0.f));
    }
  __syncthreads();  // XT updated for next layer
}

__global__ __launch_bounds__(512) void tail_fused(const float* __restrict__ P,
                                                  const unsigned short* __restrict__ Bg2,
                                                  const unsigned short* __restrict__ Bg3,
                                                  const unsigned short* __restrict__ Bg4,
                                                  const float* __restrict__ b1,
                                                  const float* __restrict__ b2,
                                                  const float* __restrict__ b3,
                                                  const float* __restrict__ b4,
                                                  const float* __restrict__ w5,
                                                  const float* __restrict__ b5,
                                                  float* __restrict__ out) {
  __shared__ __align__(16) unsigned short XT[257 * XTS];  // 37 KB
  const int b = blockIdx.x;
  const int tid = threadIdx.x;
  const int lane = tid & 63, wave = tid >> 6;
  const int quad = lane >> 4, tl = lane & 15;
  const int mw = wave >> 1, nh = wave & 1;
  const float* p0 = P + (size_t)b * 16384;
  const float* p1 = p0 + (size_t)256 * 16384;
  const float bias1 = b1[0];

  if (tid < 9) *(int4*)&XT[256 * XTS + tid * 8] = make_int4(0, 0, 0, 0);
  // stage: XT[wt][dh] = bf16(relu(P0 + P1 + b1))   (reduce_l1 folded in)
#pragma unroll
  for (int it = 0; it < 4; ++it) {
    const int i = tid + it * 512;
    const int dhp = i >> 6, wtq = i & 63;
    const float* s0 = p0 + (size_t)(2 * dhp) * 256 + wtq * 4;
    const float* s1 = p1 + (size_t)(2 * dhp) * 256 + wtq * 4;
    const float4 r0a = *(const float4*)s0;
    const float4 r0b = *(const float4*)s1;
    const float4 r1a = *(const float4*)(s0 + 256);
    const float4 r1b = *(const float4*)(s1 + 256);
    float a0[4] = {r0a.x + r0b.x, r0a.y + r0b.y, r0a.z + r0b.z, r0a.w + r0b.w};
    float a1[4] = {r1a.x + r1b.x, r1a.y + r1b.y, r1a.z + r1b.z, r1a.w + r1b.w};
#pragma unroll
    for (int j = 0; j < 4; ++j) {
      const unsigned short lo = f2bf(fmaxf(a0[j] + bias1, 0.f));
      const unsigned short hi = f2bf(fmaxf(a1[j] + bias1, 0.f));
      const unsigned int p = (unsigned int)lo | ((unsigned int)hi << 16);
      *(unsigned int*)&XT[(wtq * 4 + j) * XTS + dhp * 2] = p;
    }
  }
  __syncthreads();

  run_layer<7, 3, 49>(XT, Bg2, b2[0], mw, nh, lane, quad, tl);
  run_layer<5, 2, 25>(XT, Bg3, b3[0], mw, nh, lane, quad, tl);
  run_layer<3, 1, 9>(XT, Bg4, b4[0], mw, nh, lane, quad, tl);

  // L5: out[wt] = sigmoid(b5 + sum_dh w5[dh] * y4[wt][dh]); XT rows are wt
  if (tid < 256) {
    const int wt = tid;
    float s = b5[0];
    const unsigned short* row = &XT[wt * XTS];
#pragma unroll
    for (int k8 = 0; k8 < 8; ++k8) {
      const u32x4 v = *(const u32x4*)&row[k8 * 8];
      const unsigned int uu[4] = {(unsigned int)v.x, (unsigned int)v.y, (unsigned int)v.z,
                                  (unsigned int)v.w};
#pragma unroll
      for (int p = 0; p < 4; ++p) {
        const float lo = __uint_as_float(uu[p] << 16);
        const float hi = __uint_as_float(uu[p] & 0xFFFF0000u);
        s += lo * w5[k8 * 8 + p * 2] + hi * w5[k8 * 8 + p * 2 + 1];
      }
    }
    out[(size_t)b * 256 + wt] = 1.f / (1.f + expf(-s));
  }
}

extern "C" void kernel_launch(void* const* d_in, const int* in_sizes, int n_in,
                              void* d_out, int out_size, void* d_ws, size_t ws_size,
                              hipStream_t stream) {
  const float* corr = (const float*)d_in[0];
  const float* w1 = (const float*)d_in[1];
  const float* b1 = (const float*)d_in[2];
  const float* w2 = (const float*)d_in[3];
  const float* b2 = (const float*)d_in[4];
  const float* w3 = (const float*)d_in[5];
  const float* b3 = (const float*)d_in[6];
  const float* w4 = (const float*)d_in[7];
  const float* b4 = (const float*)d_in[8];
  const float* w5 = (const float*)d_in[9];
  const float* b5 = (const float*)d_in[10];

  // ws: [0,16M) P khalf0; [16M,32M) P khalf1; [32M,..) B matrices
  float* P = (float*)d_ws;
  unsigned short* Bg1 = (unsigned short*)((char*)d_ws + (32u << 20));
  unsigned short* Bg2 = Bg1 + (size_t)81 * 8 * 4 * 64 * 8;
  unsigned short* Bg3 = Bg2 + (size_t)49 * 2 * 4 * 64 * 8;
  unsigned short* Bg4 = Bg3 + (size_t)25 * 2 * 4 * 64 * 8;

  build_all<<<814, 256, 0, stream>>>(w1, w2, w3, w4, Bg1, Bg2, Bg3, Bg4);
  conv_l1_mfma<<<512, 256, 0, stream>>>(corr, Bg1, P);
  tail_fused<<<256, 512, 0, stream>>>(P, Bg2, Bg3, Bg4, b1, b2, b3, b4, w5, b5,
                                      (float*)d_out);
}